// Round 4
// baseline (400.877 us; speedup 1.0000x reference)
//
#include <hip/hip_runtime.h>
#include <hip/hip_bf16.h>
#include <stdint.h>

#define BATCH 8
#define SEQ   2048
#define EMB   256
#define ADIM  256

typedef __bf16 bf16_t;
typedef __attribute__((ext_vector_type(8))) __bf16 bf16x8;
typedef __attribute__((ext_vector_type(4))) float  f32x4;
typedef uint32_t u32;
typedef long long i64;

static __device__ __forceinline__ f32x4 mfma16(bf16x8 a, bf16x8 b, f32x4 c) {
    return __builtin_amdgcn_mfma_f32_16x16x32_bf16(a, b, c, 0, 0, 0);
}

// async global->LDS DMA: lds dest = wave-uniform base + lane*16
static __device__ __forceinline__ void gld16(const void* g, void* l) {
    __builtin_amdgcn_global_load_lds((const __attribute__((address_space(1))) u32*)g,
                                     (__attribute__((address_space(3))) u32*)l, 16, 0, 0);
}

// ---------------- kernel 0: W^T (k,v) cast to bf16 -> d_out scratch ----------------
// wt[m][a][e] = (bf16) W_m[e][a]. d_out is dead for flash output until the memset;
// only proj (stream-ordered before the memset) reads wt.
__global__ __launch_bounds__(256) void wtkv_kernel(const float* __restrict__ Wk,
                                                   const float* __restrict__ Wv,
                                                   bf16_t* __restrict__ wt) {
    int tid = blockIdx.x * 256 + threadIdx.x;   // 0 .. 2*65536-1
    int m = tid >> 16;
    int i = tid & 65535;
    int a = i >> 8, e = i & 255;
    const float* W = (m == 0) ? Wk : Wv;
    wt[m * 65536 + a * 256 + e] = (bf16_t)W[e * 256 + a];
}

// ---------------- kernel 1: fused K+V projection, coalesced stores ----------------
// (R0 rewrite, proven numerically identical; not a bottleneck.)
// Byte layouts consumed by flash:
//   Ksw: per batch 64 tiles x 16384 B; byte = n*512 + ((cb^(n&7))*16) + j*2
//   Vsw: byte = a*64 + (((k>>3) ^ (a&3) ^ ((a>>2)&3))*16) + (k&7)*2, k = s&31
__global__ __launch_bounds__(128, 1) void proj_kv(const float* __restrict__ x,
                                                  const bf16_t* __restrict__ wt,  // in d_out
                                                  const float* __restrict__ bk,
                                                  const float* __restrict__ bv,
                                                  char* __restrict__ Ksw,
                                                  char* __restrict__ Vsw) {
    __shared__ __align__(16) char stg[2][10240];   // per-wave repack buffer
    const int tid  = threadIdx.x;
    const int wid  = tid >> 6;
    const int lane = tid & 63;
    const int lq   = lane >> 4;
    const int ln   = lane & 15;
    const int blk  = blockIdx.x;                   // 0..511: one 32-row tile
    const int b    = blk >> 6;                     // batch
    const int tile = blk & 63;                     // tile within batch
    const int mbase = blk * 32 + wid * 16;         // this wave's 16 global rows
    char* S = stg[wid];

    bf16x8 xf[8];
    const float* xp = x + (size_t)(mbase + ln) * EMB;
    #pragma unroll
    for (int c = 0; c < 8; ++c) {
        f32x4 a0 = *(const f32x4*)(xp + c * 32 + lq * 8);
        f32x4 a1 = *(const f32x4*)(xp + c * 32 + lq * 8 + 4);
        bf16x8 v;
        v[0] = (bf16_t)a0[0]; v[1] = (bf16_t)a0[1]; v[2] = (bf16_t)a0[2]; v[3] = (bf16_t)a0[3];
        v[4] = (bf16_t)a1[0]; v[5] = (bf16_t)a1[1]; v[6] = (bf16_t)a1[2]; v[7] = (bf16_t)a1[3];
        xf[c] = v;
    }

    f32x4 acc[16];

    // ======== K projection ========
    #pragma unroll
    for (int t = 0; t < 16; ++t) acc[t] = (f32x4){0.f, 0.f, 0.f, 0.f};
    {
        const bf16_t* w = wt;                      // K panel wt[0][a][e]
        #pragma unroll
        for (int c = 0; c < 8; ++c)
            #pragma unroll
            for (int t = 0; t < 16; ++t) {
                bf16x8 wf = *(const bf16x8*)(w + (size_t)(t * 16 + ln) * 256 + c * 32 + lq * 8);
                acc[t] = mfma16(xf[c], wf, acc[t]);
            }
    }
    #pragma unroll
    for (int t = 0; t < 16; ++t) {
        float bb = bk[t * 16 + ln];
        #pragma unroll
        for (int r = 0; r < 4; ++r)
            *(bf16_t*)(S + (lq * 4 + r) * 512 + (t * 16 + ln) * 2) = (bf16_t)(acc[t][r] + bb);
    }
    asm volatile("s_waitcnt lgkmcnt(0)" ::: "memory");
    {
        char* Kg = Ksw + (size_t)b * 1048576 + (size_t)tile * 16384 + wid * 8192;
        const int rh = lane >> 5;
        const int p  = lane & 31;
        #pragma unroll
        for (int i = 0; i < 8; ++i) {
            int row = i * 2 + rh;
            int n   = wid * 16 + row;
            int cb  = p ^ (n & 7);
            f32x4 ch = *(const f32x4*)(S + row * 512 + cb * 16);
            *(f32x4*)(Kg + row * 512 + p * 16) = ch;
        }
    }

    // ======== V projection ========
    #pragma unroll
    for (int t = 0; t < 16; ++t) acc[t] = (f32x4){0.f, 0.f, 0.f, 0.f};
    {
        const bf16_t* w = wt + 65536;              // V panel wt[1][a][e]
        #pragma unroll
        for (int c = 0; c < 8; ++c)
            #pragma unroll
            for (int t = 0; t < 16; ++t) {
                bf16x8 wf = *(const bf16x8*)(w + (size_t)(t * 16 + ln) * 256 + c * 32 + lq * 8);
                acc[t] = mfma16(xf[c], wf, acc[t]);
            }
    }
    #pragma unroll
    for (int t = 0; t < 16; ++t) {
        float bb = bv[t * 16 + ln];
        #pragma unroll
        for (int r = 0; r < 4; ++r)
            *(bf16_t*)(S + (t * 16 + ln) * 40 + (lq * 4 + r) * 2) = (bf16_t)(acc[t][r] + bb);
    }
    asm volatile("s_waitcnt lgkmcnt(0)" ::: "memory");
    {
        char* Vg = Vsw + (size_t)b * 1048576 + (size_t)tile * 16384;
        const int half = lane & 1;
        const int kq   = wid * 2 + half;
        #pragma unroll
        for (int i = 0; i < 8; ++i) {
            int a   = i * 32 + (lane >> 1);
            int pos = kq ^ (a & 3) ^ ((a >> 2) & 3);
            f32x4 ch = *(const f32x4*)(S + a * 40 + half * 16);
            *(f32x4*)(Vg + a * 64 + pos * 16) = ch;
        }
    }
}

// ---------------- kernel 2: fused masked attention, 4-way KV-split ----------------
// R3 = R1's occupancy design with the spill fixed:
//   __launch_bounds__(256, 2)  (R1's (256,3) forced the allocator to ~84 VGPRs ->
//   o/qf accumulators spilled -> 1.5 GB scratch traffic. Body needs ~135 regs;
//   135 < 170 = 3-waves/SIMD ceiling, so 3 blocks/CU co-reside via LDS: 54272*3
//   = 162816 <= 163840.)
// Structure (R1-verified correct): LDS 54272 = K dbuf 32K + V single 16K + P 5K.
// V register-staged (T14): V(kt+1)->16 VGPRs during iter kt, ds_write after iter
// kt+1's top barrier (region free: all V(kt) readers crossed that barrier),
// read only after the mid lgkmcnt(0) barrier. K double-buffered via gld16 DMA.
// Grid 1024 = 32 qtiles x 4 kv-quarters x 8 batches (>=768 needed to fill 3/CU).
// No setprio (R2 measured it at -10 us on this lockstep structure).
// lsum parking via (lp,bs,rs,ks): d_ws in ws-mode (mask stays clean), in-mask
// fallback (block-private word, read-before-write).
__global__ __launch_bounds__(256, 2) void flash_kernel(const float* __restrict__ x,
                                                       const float* __restrict__ WqM,
                                                       const float* __restrict__ bq,
                                                       const char* __restrict__ Ksw,
                                                       const char* __restrict__ Vsw,
                                                       const int* __restrict__ mask,
                                                       float* __restrict__ lp,
                                                       i64 bs, i64 rs, i64 ks,
                                                       float* __restrict__ out) {
    // LDS map: K0@0 K1@16384 | V@32768 (16K, also prologue Wq scratch) |
    //          Pq/Pt@49152 (5120; Ls aliases it after the final __syncthreads).
    __shared__ __align__(16) char smem[54272];
    const int tid  = threadIdx.x;
    const int wid  = tid >> 6;
    const int lane = tid & 63;
    const int lq   = lane >> 4;
    const int ln   = lane & 15;
    const int qw   = wid >> 1;    // q half (32 rows)
    const int kw   = wid & 1;     // kv col half within tile (16 cols)
    const int batch = blockIdx.x & 7;            // XCD L2 pinning
    const int kvh   = (blockIdx.x >> 3) & 3;     // kv quarter of the sequence
    const int qbase = (blockIdx.x >> 5) * 64;

    const char* Kb = Ksw + (size_t)batch * 1048576 + (size_t)(kvh * 16) * 16384;
    const char* Vb = Vsw + (size_t)batch * 1048576 + (size_t)(kvh * 16) * 16384;
    char*  Pq_ = smem + 49152 + qw * 2560;       // shared by kw pair: 32 rows x 80 B
    char*  Pt  = smem + 49152 + wid * 1280;      // wave-private (prologue only)
    float* Ls  = (float*)(smem + 49152);         // epilogue only (aliases Pq, safe)

    const char* kg0 = Kb + wid * 4096 + lane * 16;
    const char* vg0 = Vb + wid * 4096 + lane * 16;

    // raw mask base for this wave's rows and its kv-col strip (512-col quarter)
    const int* mroot = mask + (size_t)batch * SEQ * SEQ +
                       (size_t)(qbase + qw * 32) * SEQ + kvh * 512 + kw * 16 + ln;

    // ---- issue K DMA + V reg-load for tile 0 (latency covered by Q prologue) ----
    f32x4 vr[4];
    {
        char* kl = smem + wid * 4096;            // K0
        #pragma unroll
        for (int i = 0; i < 4; ++i) gld16(kg0 + i * 1024, kl + i * 1024);
        #pragma unroll
        for (int i = 0; i < 4; ++i) vr[i] = *(const f32x4*)(vg0 + i * 1024);
    }
    // mask ring prefill for kt = 0,1 (completes during prologue)
    int mv[2][2][4];
    #pragma unroll
    for (int w = 0; w < 2; ++w)
        #pragma unroll
        for (int h = 0; h < 2; ++h)
            #pragma unroll
            for (int r = 0; r < 4; ++r)
                mv[w][h][r] = mroot[(size_t)(h * 16 + lq * 4 + r) * SEQ + w * 32];

    // ---- Q prologue: this qw's 32 rows -> A-fragments qf[h][c] ----
    // Wq staged in the V region (16 KB: row stride 64 B, 2-bit XOR swizzle;
    // R1-verified correct).
    bf16x8 qf[2][8];
    {
        bf16x8 xf[2][8];
        #pragma unroll
        for (int h = 0; h < 2; ++h) {
            const float* xp = x + (size_t)(batch * SEQ + qbase + qw * 32 + h * 16 + ln) * EMB;
            #pragma unroll
            for (int c = 0; c < 8; ++c) {
                f32x4 a = *(const f32x4*)(xp + c * 32 + lq * 8);
                f32x4 b = *(const f32x4*)(xp + c * 32 + lq * 8 + 4);
                bf16x8 v;
                v[0] = (bf16_t)a[0]; v[1] = (bf16_t)a[1]; v[2] = (bf16_t)a[2]; v[3] = (bf16_t)a[3];
                v[4] = (bf16_t)b[0]; v[5] = (bf16_t)b[1]; v[6] = (bf16_t)b[2]; v[7] = (bf16_t)b[3];
                xf[h][c] = v;
            }
        }
        f32x4 qacc[2][16];
        #pragma unroll
        for (int h = 0; h < 2; ++h)
            #pragma unroll
            for (int t = 0; t < 16; ++t) qacc[h][t] = (f32x4){0.f, 0.f, 0.f, 0.f};

        char* Wsp = smem + 32768;                // V buffer: free until kt=0 ds_write
        const int swr = (tid >> 1) & 3;          // writer swizzle term
        const int swl = (ln >> 1) & 3;           // reader reproduces it (t*8 % 4 == 0)
        #pragma unroll 1
        for (int cp = 0; cp < 8; ++cp) {
            __syncthreads();
            const float* wqp = WqM + (size_t)(cp * 32) * 256 + tid;
            #pragma unroll
            for (int i = 0; i < 4; ++i) {
                bf16x8 pk;
                #pragma unroll
                for (int j = 0; j < 8; ++j)
                    pk[j] = (bf16_t)wqp[(size_t)(i * 8 + j) * 256];
                *(bf16x8*)(Wsp + tid * 64 + ((i ^ swr) * 16)) = pk;
            }
            __syncthreads();
            #pragma unroll
            for (int t = 0; t < 16; ++t) {
                bf16x8 wf = *(const bf16x8*)(Wsp + (t * 16 + ln) * 64 + ((lq ^ swl) * 16));
                qacc[0][t] = mfma16(xf[0][cp], wf, qacc[0][t]);
                qacc[1][t] = mfma16(xf[1][cp], wf, qacc[1][t]);
            }
        }
        // C-layout -> A-layout via wave-private Pt; fold bias and 1/sqrt(A)=1/16
        #pragma unroll
        for (int h = 0; h < 2; ++h) {
            #pragma unroll
            for (int c = 0; c < 8; ++c) {
                #pragma unroll
                for (int half2 = 0; half2 < 2; ++half2) {
                    int t = 2 * c + half2;
                    float bb = bq[t * 16 + ln];
                    #pragma unroll
                    for (int r = 0; r < 4; ++r) {
                        float v = (qacc[h][t][r] + bb) * 0.0625f;
                        ((bf16_t*)(Pt + (lq * 4 + r) * 80))[half2 * 16 + ln] = (bf16_t)v;
                    }
                }
                qf[h][c] = *(const bf16x8*)(Pt + ln * 80 + lq * 16);
            }
        }
    }

    // ---- main loop: 16 iterations over this block's kv quarter ----
    f32x4 o[2][8];
    #pragma unroll
    for (int h = 0; h < 2; ++h)
        #pragma unroll
        for (int t = 0; t < 8; ++t) o[h][t] = (f32x4){0.f, 0.f, 0.f, 0.f};
    float lsum[2][4] = {{0.f,0.f,0.f,0.f},{0.f,0.f,0.f,0.f}};

    const int kswz = ln & 7;
    const int vswz = (lq ^ (ln & 3) ^ ((ln >> 2) & 3)) * 16;
    const int n0   = kw * 16 + ln;

    for (int kt = 0; kt < 16; ++kt) {
        __syncthreads();                  // drains K DMA(kt) [vmcnt0] + all prior LDS use
        // publish V(kt) from regs (region idle: readers of V(kt-1) crossed this barrier)
        {
            char* vl = smem + 32768 + wid * 4096;
            #pragma unroll
            for (int i = 0; i < 4; ++i)
                *(f32x4*)(vl + i * 1024 + lane * 16) = vr[i];
        }
        if (kt + 1 < 16) {                // prefetch tile kt+1: K -> LDS, V -> regs
            const char* kg = kg0 + (size_t)(kt + 1) * 16384;
            char* kl = smem + ((kt + 1) & 1) * 16384 + wid * 4096;
            #pragma unroll
            for (int i = 0; i < 4; ++i) gld16(kg + i * 1024, kl + i * 1024);
            const char* vg = vg0 + (size_t)(kt + 1) * 16384;
            #pragma unroll
            for (int i = 0; i < 4; ++i) vr[i] = *(const f32x4*)(vg + i * 1024);
        }
        const char* Ksb = smem + (kt & 1) * 16384;

        // S = Q K^T (this wave's 16 kv cols; both q subtiles share each K frag)
        f32x4 s0 = (f32x4){0.f,0.f,0.f,0.f};
        f32x4 s1 = (f32x4){0.f,0.f,0.f,0.f};
        const char* krow = Ksb + n0 * 512;
        #pragma unroll
        for (int c = 0; c < 8; ++c) {
            bf16x8 kf = *(const bf16x8*)(krow + (((c * 4 + lq) ^ kswz) * 16));
            s0 = mfma16(qf[0][c], kf, s0);
            s1 = mfma16(qf[1][c], kf, s1);
        }

        // p = mask ? exp(s) : 0 (ring slot loaded 2 barriers ago -> wait-free)
        const int (*mc)[4] = mv[kt & 1];
        #pragma unroll
        for (int r = 0; r < 4; ++r) {
            float p0 = mc[0][r] ? __expf(s0[r]) : 0.f;
            float p1 = mc[1][r] ? __expf(s1[r]) : 0.f;
            lsum[0][r] += p0;
            lsum[1][r] += p1;
            ((bf16_t*)(Pq_ + (lq * 4 + r) * 80))[kw * 16 + ln]      = (bf16_t)p0;
            ((bf16_t*)(Pq_ + (16 + lq * 4 + r) * 80))[kw * 16 + ln] = (bf16_t)p1;
        }

        // refill ring slot for kt+2 (clamped at tail; WAR on regs, no wait)
        {
            const int ktn = (kt + 2 < 16) ? kt + 2 : 15;
            int (*md)[4] = mv[kt & 1];
            #pragma unroll
            for (int h = 0; h < 2; ++h)
                #pragma unroll
                for (int r = 0; r < 4; ++r)
                    md[h][r] = mroot[(size_t)(h * 16 + lq * 4 + r) * SEQ + ktn * 32];
        }

        // P-exchange + V publish: drain LDS only — K prefetch DMA stays in flight
        asm volatile("s_waitcnt lgkmcnt(0)\n\ts_barrier" ::: "memory");

        bf16x8 pa0 = *(const bf16x8*)(Pq_ + ln * 80 + lq * 16);
        bf16x8 pa1 = *(const bf16x8*)(Pq_ + (16 + ln) * 80 + lq * 16);

        // O += P V (this wave's 128 a-cols; both q subtiles share each V frag)
        const char* vbase = smem + 32768 + (kw * 128 + ln) * 64 + vswz;
        #pragma unroll
        for (int t = 0; t < 8; ++t) {
            bf16x8 vf = *(const bf16x8*)(vbase + t * 1024);
            o[0][t] = mfma16(pa0, vf, o[0][t]);
            o[1][t] = mfma16(pa1, vf, o[1][t]);
        }
    }

    __syncthreads();
    // partial row-sum: reduce over the 16 ln lanes, publish, combine kw halves
    #pragma unroll
    for (int h = 0; h < 2; ++h) {
        #pragma unroll
        for (int r = 0; r < 4; ++r) {
            float v = lsum[h][r];
            v += __shfl_xor(v, 1);
            v += __shfl_xor(v, 2);
            v += __shfl_xor(v, 4);
            v += __shfl_xor(v, 8);
            if (ln == 0) Ls[(qw * 2 + kw) * 32 + h * 16 + lq * 4 + r] = v;
            lsum[h][r] = v;
        }
    }
    __syncthreads();

    // park this block's per-row partial lsum (lp: d_ws in ws-mode, mask slot fallback)
    if (kw == 0 && ln == 0) {
        #pragma unroll
        for (int h = 0; h < 2; ++h)
            #pragma unroll
            for (int r = 0; r < 4; ++r) {
                int row = h * 16 + lq * 4 + r;
                float tot = lsum[h][r] + Ls[(qw * 2 + 1) * 32 + row];
                lp[bs * batch + rs * (qbase + qw * 32 + row) + ks * kvh] = tot;
            }
    }

    // accumulate unnormalized partial O into zeroed d_out
    #pragma unroll
    for (int h = 0; h < 2; ++h) {
        #pragma unroll
        for (int r = 0; r < 4; ++r) {
            float* orow = out + (size_t)(batch * SEQ + qbase + qw * 32 + h * 16 + lq * 4 + r) * ADIM
                          + kw * 128 + ln;
            #pragma unroll
            for (int t = 0; t < 8; ++t)
                atomicAdd(orow + t * 16, o[h][t][r]);
        }
    }
}

// ---------------- kernel 3: merge/normalize ----------------
// out[row][:] /= sum of the 4 partial lsums read via (lp, strides).
__global__ __launch_bounds__(256) void merge_kernel(const float* __restrict__ lp,
                                                    i64 bs, i64 rs, i64 ks,
                                                    float* __restrict__ out) {
    int idx  = blockIdx.x * 256 + threadIdx.x;   // x4 elements
    int base = idx * 4;                          // 0 .. 16,777,212
    int row  = base >> 8;                        // global row 0..16383
    int b = row >> 11, r = row & 2047;
    const float* lb = lp + bs * b + rs * r;
    float inv = 1.0f / (lb[0] + lb[ks] + lb[2 * ks] + lb[3 * ks]);
    f32x4 v = *(const f32x4*)(out + base);
    v[0] *= inv; v[1] *= inv; v[2] *= inv; v[3] *= inv;
    *(f32x4*)(out + base) = v;
}

// ================= launch =================
extern "C" void kernel_launch(void* const* d_in, const int* in_sizes, int n_in,
                              void* d_out, int out_size, void* d_ws, size_t ws_size,
                              hipStream_t stream) {
    const float* x    = (const float*)d_in[0];
    int*         mask = (int*)d_in[1];
    const float* Wq   = (const float*)d_in[2];
    const float* bq   = (const float*)d_in[3];
    const float* Wk   = (const float*)d_in[4];
    const float* bk   = (const float*)d_in[5];
    const float* Wv   = (const float*)d_in[6];
    const float* bv   = (const float*)d_in[7];
    float* out = (float*)d_out;

    // ws: K_sw [0..8MB) | V_sw [8..16MB) | (optional) lsum park [16MB..16MB+256KB)
    char* Ksw = (char*)d_ws;
    char* Vsw = Ksw + (size_t)8 * 1024 * 1024;
    bf16_t* wt = (bf16_t*)d_out;                 // W^T bf16 scratch, consumed by proj

    // lsum parking target: prefer d_ws tail (mask input stays clean);
    // fall back to block-private in-mask slots (read-before-write) if ws is tight.
    const size_t need = (size_t)16 * 1024 * 1024 + (size_t)4 * BATCH * SEQ * sizeof(float);
    float* lp; i64 bs, rs, ks;
    if (ws_size >= need) {
        lp = (float*)(Ksw + (size_t)16 * 1024 * 1024);
        bs = (i64)4 * SEQ;  rs = 4;  ks = 1;
    } else {
        lp = (float*)mask;                        // col kvh*512 of own rows
        bs = (i64)SEQ * SEQ;  rs = SEQ;  ks = 512;
    }

    wtkv_kernel<<<512, 256, 0, stream>>>(Wk, Wv, wt);
    proj_kv<<<512, 128, 0, stream>>>(x, wt, bk, bv, Ksw, Vsw);
    // zero the f32 accumulator AFTER proj consumed wt (stream-ordered; graph-legal)
    hipMemsetAsync(d_out, 0, (size_t)out_size * sizeof(float), stream);
    flash_kernel<<<1024, 256, 0, stream>>>(x, Wq, bq, Ksw, Vsw, mask, lp, bs, rs, ks, out);
    merge_kernel<<<4096, 256, 0, stream>>>(lp, bs, rs, ks, out);
}

// Round 6
// 367.086 us; speedup vs baseline: 1.0921x; 1.0921x over previous
//
#include <hip/hip_runtime.h>
#include <hip/hip_bf16.h>
#include <stdint.h>

#define BATCH 8
#define SEQ   2048
#define EMB   256
#define ADIM  256

typedef __bf16 bf16_t;
typedef __attribute__((ext_vector_type(8))) __bf16 bf16x8;
typedef __attribute__((ext_vector_type(4))) float  f32x4;
typedef uint32_t u32;
typedef __attribute__((ext_vector_type(4))) u32 u32x4;
typedef long long i64;

static __device__ __forceinline__ f32x4 mfma16(bf16x8 a, bf16x8 b, f32x4 c) {
    return __builtin_amdgcn_mfma_f32_16x16x32_bf16(a, b, c, 0, 0, 0);
}

// async global->LDS DMA: lds dest = wave-uniform base + lane*16
static __device__ __forceinline__ void gld16(const void* g, void* l) {
    __builtin_amdgcn_global_load_lds((const __attribute__((address_space(1))) u32*)g,
                                     (__attribute__((address_space(3))) u32*)l, 16, 0, 0);
}

// ---------------- kernel 0: W^T (k,v) cast to bf16 -> d_out scratch ----------------
// wt[m][a][e] = (bf16) W_m[e][a]. d_out is dead for flash output until the memset;
// only proj (stream-ordered before the memset) reads wt.
__global__ __launch_bounds__(256) void wtkv_kernel(const float* __restrict__ Wk,
                                                   const float* __restrict__ Wv,
                                                   bf16_t* __restrict__ wt) {
    int tid = blockIdx.x * 256 + threadIdx.x;   // 0 .. 2*65536-1
    int m = tid >> 16;
    int i = tid & 65535;
    int a = i >> 8, e = i & 255;
    const float* W = (m == 0) ? Wk : Wv;
    wt[m * 65536 + a * 256 + e] = (bf16_t)W[e * 256 + a];
}

// ---------------- kernel 0b: mask -> bit-words ----------------
// bitw word idx = b*131072 + row*64 + w covers mask cols [w*32, w*32+32); bit j set
// iff mask[b][row][w*32+j] != 0. 134 MB int32 -> 4 MB (L2-resident per batch).
__global__ __launch_bounds__(256) void maskbits_kernel(const u32* __restrict__ mask,
                                                       u32* __restrict__ bitw) {
    int idx = blockIdx.x * 256 + threadIdx.x;        // 0 .. 1048575
    const u32* mp = mask + (size_t)idx * 32;         // 128 B contiguous per thread
    u32 wd = 0;
    #pragma unroll
    for (int q = 0; q < 8; ++q) {
        u32x4 v = *(const u32x4*)(mp + q * 4);
        #pragma unroll
        for (int j = 0; j < 4; ++j)
            wd |= (v[j] ? 1u : 0u) << (q * 4 + j);
    }
    bitw[idx] = wd;
}

// ---------------- kernel 1: fused K+V projection, coalesced stores ----------------
// Byte layouts consumed by flash:
//   Ksw: per batch 64 tiles x 16384 B; byte = n*512 + ((cb^(n&7))*16) + j*2
//   Vsw: byte = a*64 + (((k>>3) ^ (a&3) ^ ((a>>2)&3))*16) + (k&7)*2, k = s&31
__global__ __launch_bounds__(128, 1) void proj_kv(const float* __restrict__ x,
                                                  const bf16_t* __restrict__ wt,  // in d_out
                                                  const float* __restrict__ bk,
                                                  const float* __restrict__ bv,
                                                  char* __restrict__ Ksw,
                                                  char* __restrict__ Vsw) {
    __shared__ __align__(16) char stg[2][10240];   // per-wave repack buffer
    const int tid  = threadIdx.x;
    const int wid  = tid >> 6;
    const int lane = tid & 63;
    const int lq   = lane >> 4;
    const int ln   = lane & 15;
    const int blk  = blockIdx.x;                   // 0..511: one 32-row tile
    const int b    = blk >> 6;                     // batch
    const int tile = blk & 63;                     // tile within batch
    const int mbase = blk * 32 + wid * 16;         // this wave's 16 global rows
    char* S = stg[wid];

    bf16x8 xf[8];
    const float* xp = x + (size_t)(mbase + ln) * EMB;
    #pragma unroll
    for (int c = 0; c < 8; ++c) {
        f32x4 a0 = *(const f32x4*)(xp + c * 32 + lq * 8);
        f32x4 a1 = *(const f32x4*)(xp + c * 32 + lq * 8 + 4);
        bf16x8 v;
        v[0] = (bf16_t)a0[0]; v[1] = (bf16_t)a0[1]; v[2] = (bf16_t)a0[2]; v[3] = (bf16_t)a0[3];
        v[4] = (bf16_t)a1[0]; v[5] = (bf16_t)a1[1]; v[6] = (bf16_t)a1[2]; v[7] = (bf16_t)a1[3];
        xf[c] = v;
    }

    f32x4 acc[16];

    // ======== K projection ========
    #pragma unroll
    for (int t = 0; t < 16; ++t) acc[t] = (f32x4){0.f, 0.f, 0.f, 0.f};
    {
        const bf16_t* w = wt;                      // K panel wt[0][a][e]
        #pragma unroll
        for (int c = 0; c < 8; ++c)
            #pragma unroll
            for (int t = 0; t < 16; ++t) {
                bf16x8 wf = *(const bf16x8*)(w + (size_t)(t * 16 + ln) * 256 + c * 32 + lq * 8);
                acc[t] = mfma16(xf[c], wf, acc[t]);
            }
    }
    #pragma unroll
    for (int t = 0; t < 16; ++t) {
        float bb = bk[t * 16 + ln];
        #pragma unroll
        for (int r = 0; r < 4; ++r)
            *(bf16_t*)(S + (lq * 4 + r) * 512 + (t * 16 + ln) * 2) = (bf16_t)(acc[t][r] + bb);
    }
    asm volatile("s_waitcnt lgkmcnt(0)" ::: "memory");
    {
        char* Kg = Ksw + (size_t)b * 1048576 + (size_t)tile * 16384 + wid * 8192;
        const int rh = lane >> 5;
        const int p  = lane & 31;
        #pragma unroll
        for (int i = 0; i < 8; ++i) {
            int row = i * 2 + rh;
            int n   = wid * 16 + row;
            int cb  = p ^ (n & 7);
            f32x4 ch = *(const f32x4*)(S + row * 512 + cb * 16);
            *(f32x4*)(Kg + row * 512 + p * 16) = ch;
        }
    }

    // ======== V projection ========
    #pragma unroll
    for (int t = 0; t < 16; ++t) acc[t] = (f32x4){0.f, 0.f, 0.f, 0.f};
    {
        const bf16_t* w = wt + 65536;              // V panel wt[1][a][e]
        #pragma unroll
        for (int c = 0; c < 8; ++c)
            #pragma unroll
            for (int t = 0; t < 16; ++t) {
                bf16x8 wf = *(const bf16x8*)(w + (size_t)(t * 16 + ln) * 256 + c * 32 + lq * 8);
                acc[t] = mfma16(xf[c], wf, acc[t]);
            }
    }
    #pragma unroll
    for (int t = 0; t < 16; ++t) {
        float bb = bv[t * 16 + ln];
        #pragma unroll
        for (int r = 0; r < 4; ++r)
            *(bf16_t*)(S + (t * 16 + ln) * 40 + (lq * 4 + r) * 2) = (bf16_t)(acc[t][r] + bb);
    }
    asm volatile("s_waitcnt lgkmcnt(0)" ::: "memory");
    {
        char* Vg = Vsw + (size_t)b * 1048576 + (size_t)tile * 16384;
        const int half = lane & 1;
        const int kq   = wid * 2 + half;
        #pragma unroll
        for (int i = 0; i < 8; ++i) {
            int a   = i * 32 + (lane >> 1);
            int pos = kq ^ (a & 3) ^ ((a >> 2) & 3);
            f32x4 ch = *(const f32x4*)(S + a * 40 + half * 16);
            *(f32x4*)(Vg + a * 64 + pos * 16) = ch;
        }
    }
}

// ---------------- kernel 2: fused masked attention, KV-split ----------------
// R0-proven body (175 us: LDS 71168, 2 blocks/CU, grid 512 = 32 qtiles x 2 kvh x
// 8 batches, K/V double-buffered via gld16 DMA, depth-2 mask register ring).
// R4 deltas:
//   (a) TOP barrier is counted: s_waitcnt vmcnt(8) lgkmcnt(0); s_barrier.
//       Per wave per iter the vmem order is [8 gld16 DMA][8 mask/word loads];
//       vmcnt decrements in-order, so vmcnt(8) retires the DMA while the young
//       mask loads stay in flight ACROSS the barrier (was: vmcnt(0) drained a
//       half-iteration-old HBM stream every iter, all waves parked together).
//       The ring refill sits between the two asm barriers (memory clobbers pin
//       it), so the after-DMA count is exactly 8 by construction.
//   (b) mask ring can read 32-col bit-words from maskbits (L2-resident 512 KB
//       per batch) instead of raw int32 rows; bitw==nullptr falls back to raw.
//   (c) no setprio (R2: -10 us on this lockstep structure).
__global__ __launch_bounds__(256, 2) void flash_kernel(const float* __restrict__ x,
                                                       const float* __restrict__ WqM,
                                                       const float* __restrict__ bq,
                                                       const char* __restrict__ Ksw,
                                                       const char* __restrict__ Vsw,
                                                       const int* __restrict__ mask,
                                                       const u32* __restrict__ bitw,
                                                       float* __restrict__ lp,
                                                       i64 bs, i64 rs, i64 ks,
                                                       float* __restrict__ out) {
    // LDS: [K0 16K][V0 16K][K1 16K][V1 16K] @0 ; Pq 2x2560 @65536 (aliases prologue
    // Pt 4x1280 — safe: last Pt read precedes the kt=0 top barrier) ; Ls 512 @70656.
    __shared__ __align__(16) char smem[71168];
    const int tid  = threadIdx.x;
    const int wid  = tid >> 6;
    const int lane = tid & 63;
    const int lq   = lane >> 4;
    const int ln   = lane & 15;
    const int qw   = wid >> 1;    // q half (32 rows)
    const int kw   = wid & 1;     // kv col half within tile (16 cols)
    const int batch = blockIdx.x & 7;
    const int kvh   = (blockIdx.x >> 3) & 1;     // kv half of the sequence
    const int qbase = (blockIdx.x >> 4) * 64;

    const char* Kb = Ksw + (size_t)batch * 1048576 + (size_t)(kvh * 32) * 16384;
    const char* Vb = Vsw + (size_t)batch * 1048576 + (size_t)(kvh * 32) * 16384;
    char*  Pq_ = smem + 65536 + qw * 2560;       // shared by kw pair: 32 rows x 80 B
    char*  Pt  = smem + 65536 + wid * 1280;      // wave-private (prologue only)
    float* Ls  = (float*)(smem + 70656);

    const char* kg0 = Kb + wid * 4096 + lane * 16;
    const char* vg0 = Vb + wid * 4096 + lane * 16;

    // raw mask base for this wave's rows and its kv-col strip
    const int* mroot = mask + (size_t)batch * SEQ * SEQ +
                       (size_t)(qbase + qw * 32) * SEQ + kvh * 1024 + kw * 16 + ln;
    // bit-word base: word index = row*64 + kvh*32 + kt ; bit = kw*16 + ln
    const u32* broot = bitw ? bitw + (size_t)batch * 131072 +
                              (size_t)(qbase + qw * 32) * 64 + kvh * 32
                            : nullptr;
    const int bitpos = kw * 16 + ln;

    // ---- issue DMA for tile 0 (latency covered by Q prologue) ----
    {
        char* kl = smem + wid * 4096;
        char* vl = smem + 16384 + wid * 4096;
        #pragma unroll
        for (int i = 0; i < 4; ++i) gld16(kg0 + i * 1024, kl + i * 1024);
        #pragma unroll
        for (int i = 0; i < 4; ++i) gld16(vg0 + i * 1024, vl + i * 1024);
    }
    // pin the prefills AFTER the DMA in issue order (keeps vmcnt counting sound)
    asm volatile("" ::: "memory");
    // mask ring prefill for kt = 0,1 (completes during prologue)
    int mv[2][2][4];
    if (broot) {
        #pragma unroll
        for (int w = 0; w < 2; ++w)
            #pragma unroll
            for (int h = 0; h < 2; ++h)
                #pragma unroll
                for (int r = 0; r < 4; ++r)
                    mv[w][h][r] = (int)((broot[(h * 16 + lq * 4 + r) * 64 + w] >> bitpos) & 1u);
    } else {
        #pragma unroll
        for (int w = 0; w < 2; ++w)
            #pragma unroll
            for (int h = 0; h < 2; ++h)
                #pragma unroll
                for (int r = 0; r < 4; ++r)
                    mv[w][h][r] = mroot[(size_t)(h * 16 + lq * 4 + r) * SEQ + w * 32];
    }

    // ---- Q prologue: this qw's 32 rows -> A-fragments qf[h][c] ----
    bf16x8 qf[2][8];
    {
        bf16x8 xf[2][8];
        #pragma unroll
        for (int h = 0; h < 2; ++h) {
            const float* xp = x + (size_t)(batch * SEQ + qbase + qw * 32 + h * 16 + ln) * EMB;
            #pragma unroll
            for (int c = 0; c < 8; ++c) {
                f32x4 a = *(const f32x4*)(xp + c * 32 + lq * 8);
                f32x4 b = *(const f32x4*)(xp + c * 32 + lq * 8 + 4);
                bf16x8 v;
                v[0] = (bf16_t)a[0]; v[1] = (bf16_t)a[1]; v[2] = (bf16_t)a[2]; v[3] = (bf16_t)a[3];
                v[4] = (bf16_t)b[0]; v[5] = (bf16_t)b[1]; v[6] = (bf16_t)b[2]; v[7] = (bf16_t)b[3];
                xf[h][c] = v;
            }
        }
        f32x4 qacc[2][16];
        #pragma unroll
        for (int h = 0; h < 2; ++h)
            #pragma unroll
            for (int t = 0; t < 16; ++t) qacc[h][t] = (f32x4){0.f, 0.f, 0.f, 0.f};

        char* Wsp = smem + 32768;                // buf1 as panel scratch (tile1 DMA is later)
        const int e = ln & 7;
        #pragma unroll 1
        for (int cp = 0; cp < 8; ++cp) {
            __syncthreads();
            const float* wqp = WqM + (size_t)(cp * 32) * 256 + tid;
            #pragma unroll
            for (int i = 0; i < 4; ++i) {
                bf16x8 pk;
                #pragma unroll
                for (int j = 0; j < 8; ++j)
                    pk[j] = (bf16_t)wqp[(size_t)(i * 8 + j) * 256];
                *(bf16x8*)(Wsp + tid * 128 + ((i ^ (tid & 7)) * 16)) = pk;
            }
            __syncthreads();
            #pragma unroll
            for (int t = 0; t < 16; ++t) {
                bf16x8 wf = *(const bf16x8*)(Wsp + (t * 16 + ln) * 128 + ((lq ^ e) * 16));
                qacc[0][t] = mfma16(xf[0][cp], wf, qacc[0][t]);
                qacc[1][t] = mfma16(xf[1][cp], wf, qacc[1][t]);
            }
        }
        // C-layout -> A-layout via wave-private Pt; fold bias and 1/sqrt(A)=1/16
        #pragma unroll
        for (int h = 0; h < 2; ++h) {
            #pragma unroll
            for (int c = 0; c < 8; ++c) {
                #pragma unroll
                for (int half2 = 0; half2 < 2; ++half2) {
                    int t = 2 * c + half2;
                    float bb = bq[t * 16 + ln];
                    #pragma unroll
                    for (int r = 0; r < 4; ++r) {
                        float v = (qacc[h][t][r] + bb) * 0.0625f;
                        ((bf16_t*)(Pt + (lq * 4 + r) * 80))[half2 * 16 + ln] = (bf16_t)v;
                    }
                }
                qf[h][c] = *(const bf16x8*)(Pt + ln * 80 + lq * 16);
            }
        }
    }

    // ---- main loop: 32 iterations over this block's kv half ----
    f32x4 o[2][8];
    #pragma unroll
    for (int h = 0; h < 2; ++h)
        #pragma unroll
        for (int t = 0; t < 8; ++t) o[h][t] = (f32x4){0.f, 0.f, 0.f, 0.f};
    float lsum[2][4] = {{0.f,0.f,0.f,0.f},{0.f,0.f,0.f,0.f}};

    const int kswz = ln & 7;
    const int vswz = (lq ^ (ln & 3) ^ ((ln >> 2) & 3)) * 16;
    const int n0   = kw * 16 + ln;

    for (int kt = 0; kt < 32; ++kt) {
        // counted TOP barrier: retire the 8 DMA for tile kt (oldest), keep the
        // young mask/word loads in flight; drain own LDS ops (Pq/V WAR safety).
        asm volatile("s_waitcnt vmcnt(8) lgkmcnt(0)\n\ts_barrier" ::: "memory");
        if (kt + 1 < 32) {                        // prefetch tile kt+1
            int nb = (kt + 1) & 1;
            const char* kg = kg0 + (size_t)(kt + 1) * 16384;
            const char* vg = vg0 + (size_t)(kt + 1) * 16384;
            char* kl = smem + nb * 32768 + wid * 4096;
            char* vl = smem + nb * 32768 + 16384 + wid * 4096;
            #pragma unroll
            for (int i = 0; i < 4; ++i) gld16(kg + i * 1024, kl + i * 1024);
            #pragma unroll
            for (int i = 0; i < 4; ++i) gld16(vg + i * 1024, vl + i * 1024);
        }
        const int buf = kt & 1;
        const char* Ksb = smem + buf * 32768;
        const char* Vsb = smem + buf * 32768 + 16384;

        // S = Q K^T (this wave's 16 kv cols; both q subtiles share each K frag)
        f32x4 s0 = (f32x4){0.f,0.f,0.f,0.f};
        f32x4 s1 = (f32x4){0.f,0.f,0.f,0.f};
        const char* krow = Ksb + n0 * 512;
        #pragma unroll
        for (int c = 0; c < 8; ++c) {
            bf16x8 kf = *(const bf16x8*)(krow + (((c * 4 + lq) ^ kswz) * 16));
            s0 = mfma16(qf[0][c], kf, s0);
            s1 = mfma16(qf[1][c], kf, s1);
        }

        // p = mask ? exp(s) : 0 (ring slot loaded 1.5 iters ago -> wait-free)
        const int (*mc)[4] = mv[kt & 1];
        #pragma unroll
        for (int r = 0; r < 4; ++r) {
            float p0 = mc[0][r] ? __expf(s0[r]) : 0.f;
            float p1 = mc[1][r] ? __expf(s1[r]) : 0.f;
            lsum[0][r] += p0;
            lsum[1][r] += p1;
            ((bf16_t*)(Pq_ + (lq * 4 + r) * 80))[kw * 16 + ln]      = (bf16_t)p0;
            ((bf16_t*)(Pq_ + (16 + lq * 4 + r) * 80))[kw * 16 + ln] = (bf16_t)p1;
        }

        // P-exchange: drain LDS only — prefetch DMA stays in flight
        asm volatile("s_waitcnt lgkmcnt(0)\n\ts_barrier" ::: "memory");

        // refill ring slot for kt+2 — BETWEEN the asm barriers, so these 8 loads
        // are provably the only post-DMA vmem ops (top barrier's vmcnt(8)).
        {
            const int ktn = (kt + 2 < 32) ? kt + 2 : 31;
            int (*md)[4] = mv[kt & 1];
            if (broot) {
                #pragma unroll
                for (int h = 0; h < 2; ++h)
                    #pragma unroll
                    for (int r = 0; r < 4; ++r)
                        md[h][r] = (int)((broot[(h * 16 + lq * 4 + r) * 64 + ktn] >> bitpos) & 1u);
            } else {
                #pragma unroll
                for (int h = 0; h < 2; ++h)
                    #pragma unroll
                    for (int r = 0; r < 4; ++r)
                        md[h][r] = mroot[(size_t)(h * 16 + lq * 4 + r) * SEQ + ktn * 32];
            }
        }

        bf16x8 pa0 = *(const bf16x8*)(Pq_ + ln * 80 + lq * 16);
        bf16x8 pa1 = *(const bf16x8*)(Pq_ + (16 + ln) * 80 + lq * 16);

        // O += P V (this wave's 128 a-cols; both q subtiles share each V frag)
        const char* vbase = Vsb + (kw * 128 + ln) * 64 + vswz;
        #pragma unroll
        for (int t = 0; t < 8; ++t) {
            bf16x8 vf = *(const bf16x8*)(vbase + t * 1024);
            o[0][t] = mfma16(pa0, vf, o[0][t]);
            o[1][t] = mfma16(pa1, vf, o[1][t]);
        }
    }

    __syncthreads();
    // partial row-sum: reduce over the 16 ln lanes, publish, combine kw halves
    #pragma unroll
    for (int h = 0; h < 2; ++h) {
        #pragma unroll
        for (int r = 0; r < 4; ++r) {
            float v = lsum[h][r];
            v += __shfl_xor(v, 1);
            v += __shfl_xor(v, 2);
            v += __shfl_xor(v, 4);
            v += __shfl_xor(v, 8);
            if (ln == 0) Ls[(qw * 2 + kw) * 32 + h * 16 + lq * 4 + r] = v;
            lsum[h][r] = v;
        }
    }
    __syncthreads();

    // park this block's per-row partial lsum (lp: d_ws in ws-mode, mask slot fallback)
    if (kw == 0 && ln == 0) {
        #pragma unroll
        for (int h = 0; h < 2; ++h)
            #pragma unroll
            for (int r = 0; r < 4; ++r) {
                int row = h * 16 + lq * 4 + r;
                float tot = lsum[h][r] + Ls[(qw * 2 + 1) * 32 + row];
                lp[bs * batch + rs * (qbase + qw * 32 + row) + ks * kvh] = tot;
            }
    }

    // accumulate unnormalized partial O into zeroed d_out
    #pragma unroll
    for (int h = 0; h < 2; ++h) {
        #pragma unroll
        for (int r = 0; r < 4; ++r) {
            float* orow = out + (size_t)(batch * SEQ + qbase + qw * 32 + h * 16 + lq * 4 + r) * ADIM
                          + kw * 128 + ln;
            #pragma unroll
            for (int t = 0; t < 8; ++t)
                atomicAdd(orow + t * 16, o[h][t][r]);
        }
    }
}

// ---------------- kernel 3: merge/normalize ----------------
// out[row][:] /= (l0[row] + l1[row]) with partial lsums read via (lp, strides).
__global__ __launch_bounds__(256) void merge_kernel(const float* __restrict__ lp,
                                                    i64 bs, i64 rs, i64 ks,
                                                    float* __restrict__ out) {
    int idx  = blockIdx.x * 256 + threadIdx.x;   // x4 elements
    int base = idx * 4;                          // 0 .. 16,777,212
    int row  = base >> 8;                        // global row 0..16383
    int b = row >> 11, r = row & 2047;
    float l0 = lp[bs * b + rs * r];
    float l1 = lp[bs * b + rs * r + ks];
    float inv = 1.0f / (l0 + l1);
    f32x4 v = *(const f32x4*)(out + base);
    v[0] *= inv; v[1] *= inv; v[2] *= inv; v[3] *= inv;
    *(f32x4*)(out + base) = v;
}

// ================= launch =================
extern "C" void kernel_launch(void* const* d_in, const int* in_sizes, int n_in,
                              void* d_out, int out_size, void* d_ws, size_t ws_size,
                              hipStream_t stream) {
    const float* x    = (const float*)d_in[0];
    int*         mask = (int*)d_in[1];
    const float* Wq   = (const float*)d_in[2];
    const float* bq   = (const float*)d_in[3];
    const float* Wk   = (const float*)d_in[4];
    const float* bk   = (const float*)d_in[5];
    const float* Wv   = (const float*)d_in[6];
    const float* bv   = (const float*)d_in[7];
    float* out = (float*)d_out;

    // ws: K_sw [0..8MB) | V_sw [8..16MB) | bitw [16..20MB) | lsum park [20MB..+128KB)
    char* Ksw = (char*)d_ws;
    char* Vsw = Ksw + (size_t)8 * 1024 * 1024;
    bf16_t* wt = (bf16_t*)d_out;                 // W^T bf16 scratch, consumed by proj

    const size_t MB = 1024 * 1024;
    const size_t lsum_bytes = (size_t)2 * BATCH * SEQ * sizeof(float);   // 128 KB
    u32*   bitw = nullptr;
    float* lp; i64 bs, rs, ks;
    if (ws_size >= 20 * MB + lsum_bytes) {       // bit-mask tier
        bitw = (u32*)(Ksw + 16 * MB);
        lp = (float*)(Ksw + 20 * MB);
        bs = (i64)2 * SEQ;  rs = 2;  ks = 1;
    } else if (ws_size >= 16 * MB + lsum_bytes) { // R2-proven ws-lsum tier
        lp = (float*)(Ksw + 16 * MB);
        bs = (i64)2 * SEQ;  rs = 2;  ks = 1;
    } else {                                      // legacy in-mask parking
        lp = (float*)mask;
        bs = (i64)SEQ * SEQ;  rs = SEQ;  ks = 1024;
    }

    wtkv_kernel<<<512, 256, 0, stream>>>(Wk, Wv, wt);
    if (bitw) maskbits_kernel<<<4096, 256, 0, stream>>>((const u32*)mask, bitw);
    proj_kv<<<512, 128, 0, stream>>>(x, wt, bk, bv, Ksw, Vsw);
    // zero the f32 accumulator AFTER proj consumed wt (stream-ordered; graph-legal)
    hipMemsetAsync(d_out, 0, (size_t)out_size * sizeof(float), stream);
    flash_kernel<<<512, 256, 0, stream>>>(x, Wq, bq, Ksw, Vsw, mask, bitw,
                                          lp, bs, rs, ks, out);
    merge_kernel<<<4096, 256, 0, stream>>>(lp, bs, rs, ks, out);
}